// Round 1
// baseline (10490.250 us; speedup 1.0000x reference)
//
#include <hip/hip_runtime.h>

#define D 2048
#define DD ((size_t)D * (size_t)D)
#define TILE 128
#define KS 16

// ---------------------------------------------------------------------------
// init: bu/bl from layer 5 biases; best_ub/best_lb (in d_out) from layer-5 ub/lb
// ---------------------------------------------------------------------------
__global__ void init_vecs(const float* __restrict__ b_upper5,
                          const float* __restrict__ b_lower5,
                          const float* __restrict__ ub5,
                          const float* __restrict__ lb5,
                          float* __restrict__ bu, float* __restrict__ bl,
                          float* __restrict__ out /* [best_ub | best_lb] */) {
  int t = blockIdx.x * blockDim.x + threadIdx.x;
  if (t < D) {
    bu[t] = b_upper5[t];
    bl[t] = b_lower5[t];
    out[t] = ub5[t];
    out[D + t] = lb5[t];
  }
}

// ---------------------------------------------------------------------------
// Fused concretize + bias backsubstitution for layer i.
// One block per row r. Reads Wu[r,:], Wl[r,:] once; computes
//   cur_ub = pos(Wu_r).ub_i + neg(Wu_r).lb_i + bu[r]   -> best_ub = min
//   cur_lb = pos(Wl_r).lb_i + neg(Wl_r).ub_i + bl[r]   -> best_lb = max
//   bu[r] += pos(Wu_r).b_up_i + neg(Wu_r).b_lo_i   (if update_bias)
//   bl[r] += pos(Wl_r).b_lo_i + neg(Wl_r).b_up_i
// Uses OLD bu/bl for cur_* (matches reference order).
// ---------------------------------------------------------------------------
__global__ __launch_bounds__(256) void concretize(
    const float* __restrict__ Wu, const float* __restrict__ Wl,
    const float* __restrict__ ubi, const float* __restrict__ lbi,
    const float* __restrict__ bupi, const float* __restrict__ bloi,
    float* __restrict__ bu, float* __restrict__ bl,
    float* __restrict__ best, int update_bias) {
  int r = blockIdx.x;
  int t = threadIdx.x;
  const float* wur = Wu + (size_t)r * D;
  const float* wlr = Wl + (size_t)r * D;
  float su_c = 0.f, su_b = 0.f, sl_c = 0.f, sl_b = 0.f;
  for (int c = t; c < D; c += 256) {
    float wu = wur[c], wl = wlr[c];
    float u = ubi[c], l = lbi[c], pb = bupi[c], nb = bloi[c];
    su_c += wu * (wu >= 0.f ? u : l);
    su_b += wu * (wu >= 0.f ? pb : nb);
    sl_c += wl * (wl >= 0.f ? l : u);
    sl_b += wl * (wl >= 0.f ? nb : pb);
  }
  #pragma unroll
  for (int off = 32; off; off >>= 1) {
    su_c += __shfl_down(su_c, off);
    su_b += __shfl_down(su_b, off);
    sl_c += __shfl_down(sl_c, off);
    sl_b += __shfl_down(sl_b, off);
  }
  __shared__ float red[4][4];
  int wave = t >> 6;
  if ((t & 63) == 0) {
    red[0][wave] = su_c; red[1][wave] = su_b;
    red[2][wave] = sl_c; red[3][wave] = sl_b;
  }
  __syncthreads();
  if (t == 0) {
    float a = red[0][0] + red[0][1] + red[0][2] + red[0][3];
    float b = red[1][0] + red[1][1] + red[1][2] + red[1][3];
    float c = red[2][0] + red[2][1] + red[2][2] + red[2][3];
    float d = red[3][0] + red[3][1] + red[3][2] + red[3][3];
    float bu_old = bu[r], bl_old = bl[r];
    best[r]     = fminf(best[r],     a + bu_old);
    best[D + r] = fmaxf(best[D + r], c + bl_old);
    if (update_bias) {
      bu[r] = b + bu_old;
      bl[r] = d + bl_old;
    }
  }
}

// ---------------------------------------------------------------------------
// Symbolic matrix composition (the big GEMM):
//   z==0: Cu = pos(Au)@Wup + neg(Au)@Wlo
//   z==1: Cl = pos(Al)@Wlo + neg(Al)@Wup
// 128x128 tile, 256 threads, 8x8 microtile, KS=16 k-step, f32 vector FMA.
// ---------------------------------------------------------------------------
__global__ __launch_bounds__(256) void update_W(
    const float* __restrict__ Au, const float* __restrict__ Al,
    const float* __restrict__ Wup, const float* __restrict__ Wlo,
    float* __restrict__ Cu, float* __restrict__ Cl) {
  const float* A; const float* Bp; const float* Bn; float* C;
  if (blockIdx.z == 0) { A = Au; Bp = Wup; Bn = Wlo; C = Cu; }
  else                 { A = Al; Bp = Wlo; Bn = Wup; C = Cl; }

  const int row0 = blockIdx.y * TILE;
  const int col0 = blockIdx.x * TILE;

  __shared__ float As [KS][TILE + 4];   // transposed A tile: As[k][m]
  __shared__ float Bps[KS][TILE + 4];
  __shared__ float Bns[KS][TILE + 4];

  const int tid = threadIdx.x;
  const int tx = tid & 15;    // output col group
  const int ty = tid >> 4;    // output row group

  const int arow = tid >> 1;            // 0..127
  const int akq  = (tid & 1) * 8;       // 0 or 8
  const int brow = tid >> 4;            // 0..15
  const int bcc  = (tid & 15) * 8;      // 0..120

  const float* aptr  = A  + (size_t)(row0 + arow) * D + akq;
  const float* bpptr = Bp + (size_t)brow * D + col0 + bcc;
  const float* bnptr = Bn + (size_t)brow * D + col0 + bcc;

  float acc[8][8] = {{0.f}};

  for (int kt = 0; kt < D; kt += KS) {
    float4 a0 = *(const float4*)(aptr + kt);
    float4 a1 = *(const float4*)(aptr + kt + 4);
    float4 p0 = *(const float4*)(bpptr + (size_t)kt * D);
    float4 p1 = *(const float4*)(bpptr + (size_t)kt * D + 4);
    float4 n0 = *(const float4*)(bnptr + (size_t)kt * D);
    float4 n1 = *(const float4*)(bnptr + (size_t)kt * D + 4);

    As[akq + 0][arow] = a0.x; As[akq + 1][arow] = a0.y;
    As[akq + 2][arow] = a0.z; As[akq + 3][arow] = a0.w;
    As[akq + 4][arow] = a1.x; As[akq + 5][arow] = a1.y;
    As[akq + 6][arow] = a1.z; As[akq + 7][arow] = a1.w;
    *(float4*)&Bps[brow][bcc]     = p0;
    *(float4*)&Bps[brow][bcc + 4] = p1;
    *(float4*)&Bns[brow][bcc]     = n0;
    *(float4*)&Bns[brow][bcc + 4] = n1;
    __syncthreads();

    #pragma unroll
    for (int k = 0; k < KS; ++k) {
      float4 av0 = *(const float4*)&As [k][ty * 8];
      float4 av1 = *(const float4*)&As [k][ty * 8 + 4];
      float4 bp0 = *(const float4*)&Bps[k][tx * 8];
      float4 bp1 = *(const float4*)&Bps[k][tx * 8 + 4];
      float4 bn0 = *(const float4*)&Bns[k][tx * 8];
      float4 bn1 = *(const float4*)&Bns[k][tx * 8 + 4];
      float am[8] = {av0.x, av0.y, av0.z, av0.w, av1.x, av1.y, av1.z, av1.w};
      float bp[8] = {bp0.x, bp0.y, bp0.z, bp0.w, bp1.x, bp1.y, bp1.z, bp1.w};
      float bn[8] = {bn0.x, bn0.y, bn0.z, bn0.w, bn1.x, bn1.y, bn1.z, bn1.w};
      #pragma unroll
      for (int m = 0; m < 8; ++m) {
        float ap = fmaxf(am[m], 0.f);
        float an = fminf(am[m], 0.f);
        #pragma unroll
        for (int n = 0; n < 8; ++n)
          acc[m][n] += ap * bp[n] + an * bn[n];
      }
    }
    __syncthreads();
  }

  #pragma unroll
  for (int m = 0; m < 8; ++m) {
    float* crow = C + (size_t)(row0 + ty * 8 + m) * D + col0 + tx * 8;
    float4 c0 = {acc[m][0], acc[m][1], acc[m][2], acc[m][3]};
    float4 c1 = {acc[m][4], acc[m][5], acc[m][6], acc[m][7]};
    *(float4*)crow       = c0;
    *(float4*)(crow + 4) = c1;
  }
}

// ---------------------------------------------------------------------------
extern "C" void kernel_launch(void* const* d_in, const int* in_sizes, int n_in,
                              void* d_out, int out_size, void* d_ws, size_t ws_size,
                              hipStream_t stream) {
  const float* W_upper = (const float*)d_in[0];
  const float* W_lower = (const float*)d_in[1];
  const float* b_upper = (const float*)d_in[2];
  const float* b_lower = (const float*)d_in[3];
  const float* ub      = (const float*)d_in[4];
  const float* lb      = (const float*)d_in[5];
  float* out = (float*)d_out;  // [best_ub(2048) | best_lb(2048)]
  float* ws  = (float*)d_ws;

  float* bufU[2] = {ws,          ws + DD};
  float* bufL[2] = {ws + 2 * DD, ws + 3 * DD};
  float* bu = ws + 4 * DD;
  float* bl = bu + D;

  init_vecs<<<(D + 255) / 256, 256, 0, stream>>>(
      b_upper + 5 * D, b_lower + 5 * D, ub + 5 * D, lb + 5 * D, bu, bl, out);

  const float* curU = W_upper + 5 * DD;
  const float* curL = W_lower + 5 * DD;
  int cur = 0;
  for (int i = 4; i >= 0; --i) {
    concretize<<<D, 256, 0, stream>>>(curU, curL, ub + i * D, lb + i * D,
                                      b_upper + i * D, b_lower + i * D,
                                      bu, bl, out, 1);
    dim3 grid(D / TILE, D / TILE, 2);
    update_W<<<grid, 256, 0, stream>>>(curU, curL,
                                       W_upper + (size_t)i * DD,
                                       W_lower + (size_t)i * DD,
                                       bufU[cur], bufL[cur]);
    curU = bufU[cur]; curL = bufL[cur];
    cur ^= 1;
  }
  // final concretization against input-layer bounds (layer 0)
  concretize<<<D, 256, 0, stream>>>(curU, curL, ub, lb,
                                    b_upper, b_lower, bu, bl, out, 0);
}

// Round 4
// 657.311 us; speedup vs baseline: 15.9593x; 15.9593x over previous
//
#include <hip/hip_runtime.h>

#define D 2048
#define DD ((size_t)D * (size_t)D)

typedef __attribute__((ext_vector_type(8))) short bf16x8;
typedef __attribute__((ext_vector_type(4))) float f32x4;

#define GLOBAL_AS __attribute__((address_space(1)))
#define LDS_AS __attribute__((address_space(3)))

__device__ inline unsigned short f2bf(float f) {
  unsigned u = __float_as_uint(f);
  u += 0x7fffu + ((u >> 16) & 1u);
  return (unsigned short)(u >> 16);
}

// ---------------------------------------------------------------------------
__global__ void init_vecs(const float* __restrict__ b_upper5,
                          const float* __restrict__ b_lower5,
                          const float* __restrict__ ub5,
                          const float* __restrict__ lb5,
                          float* __restrict__ bu, float* __restrict__ bl,
                          float* __restrict__ out) {
  int t = blockIdx.x * blockDim.x + threadIdx.x;
  if (t < D) {
    bu[t] = b_upper5[t];
    bl[t] = b_lower5[t];
    out[t] = ub5[t];
    out[D + t] = lb5[t];
  }
}

// ---------------------------------------------------------------------------
// concretize: f32, one block per output row. Unchanged from round 1 (correct).
// ---------------------------------------------------------------------------
__global__ __launch_bounds__(256) void concretize(
    const float* __restrict__ Wu, const float* __restrict__ Wl,
    const float* __restrict__ ubi, const float* __restrict__ lbi,
    const float* __restrict__ bupi, const float* __restrict__ bloi,
    float* __restrict__ bu, float* __restrict__ bl,
    float* __restrict__ best, int update_bias) {
  int r = blockIdx.x;
  int t = threadIdx.x;
  const float* wur = Wu + (size_t)r * D;
  const float* wlr = Wl + (size_t)r * D;
  float su_c = 0.f, su_b = 0.f, sl_c = 0.f, sl_b = 0.f;
  for (int c = t; c < D; c += 256) {
    float wu = wur[c], wl = wlr[c];
    float u = ubi[c], l = lbi[c], pb = bupi[c], nb = bloi[c];
    su_c += wu * (wu >= 0.f ? u : l);
    su_b += wu * (wu >= 0.f ? pb : nb);
    sl_c += wl * (wl >= 0.f ? l : u);
    sl_b += wl * (wl >= 0.f ? nb : pb);
  }
  #pragma unroll
  for (int off = 32; off; off >>= 1) {
    su_c += __shfl_down(su_c, off);
    su_b += __shfl_down(su_b, off);
    sl_c += __shfl_down(sl_c, off);
    sl_b += __shfl_down(sl_b, off);
  }
  __shared__ float red[4][4];
  int wave = t >> 6;
  if ((t & 63) == 0) {
    red[0][wave] = su_c; red[1][wave] = su_b;
    red[2][wave] = sl_c; red[3][wave] = sl_b;
  }
  __syncthreads();
  if (t == 0) {
    float a = red[0][0] + red[0][1] + red[0][2] + red[0][3];
    float b = red[1][0] + red[1][1] + red[1][2] + red[1][3];
    float c = red[2][0] + red[2][1] + red[2][2] + red[2][3];
    float d = red[3][0] + red[3][1] + red[3][2] + red[3][3];
    float bu_old = bu[r], bl_old = bl[r];
    best[r]     = fminf(best[r],     a + bu_old);
    best[D + r] = fmaxf(best[D + r], c + bl_old);
    if (update_bias) {
      bu[r] = b + bu_old;
      bl[r] = d + bl_old;
    }
  }
}

// ---------------------------------------------------------------------------
// conv_A: f32 -> bf16 (row-major, elementwise). 8 elems/thread/matrix.
// ---------------------------------------------------------------------------
__global__ __launch_bounds__(256) void conv_A(const float* __restrict__ U,
                                              const float* __restrict__ Lo,
                                              unsigned short* __restrict__ oU,
                                              unsigned short* __restrict__ oL) {
  size_t b = ((size_t)blockIdx.x * 256 + threadIdx.x) * 8;
  float4 u0 = *(const float4*)(U + b), u1 = *(const float4*)(U + b + 4);
  float4 l0 = *(const float4*)(Lo + b), l1 = *(const float4*)(Lo + b + 4);
  uint4 w;
  w.x = f2bf(u0.x) | ((unsigned)f2bf(u0.y) << 16);
  w.y = f2bf(u0.z) | ((unsigned)f2bf(u0.w) << 16);
  w.z = f2bf(u1.x) | ((unsigned)f2bf(u1.y) << 16);
  w.w = f2bf(u1.z) | ((unsigned)f2bf(u1.w) << 16);
  *(uint4*)(oU + b) = w;
  w.x = f2bf(l0.x) | ((unsigned)f2bf(l0.y) << 16);
  w.y = f2bf(l0.z) | ((unsigned)f2bf(l0.w) << 16);
  w.z = f2bf(l1.x) | ((unsigned)f2bf(l1.y) << 16);
  w.w = f2bf(l1.z) | ((unsigned)f2bf(l1.w) << 16);
  *(uint4*)(oL + b) = w;
}

// ---------------------------------------------------------------------------
// conv_B: Bs = (Wup+Wlo)/2, Bd = (Wup-Wlo)/2, written TRANSPOSED ([col][k])
// so GEMM B-fragments are contiguous in K. 64x64 tile via LDS.
// ---------------------------------------------------------------------------
__global__ __launch_bounds__(256) void conv_B(const float* __restrict__ Wup,
                                              const float* __restrict__ Wlo,
                                              unsigned short* __restrict__ BsT,
                                              unsigned short* __restrict__ BdT) {
  __shared__ unsigned short sS[64][68];
  __shared__ unsigned short sD[64][68];
  const int k0 = blockIdx.y * 64, c0 = blockIdx.x * 64;
  const int tx = threadIdx.x & 15, ty = threadIdx.x >> 4;
  #pragma unroll
  for (int r = 0; r < 4; ++r) {
    int kk = ty + r * 16;
    size_t g = (size_t)(k0 + kk) * D + c0 + tx * 4;
    float4 up = *(const float4*)(Wup + g);
    float4 lo = *(const float4*)(Wlo + g);
    sS[kk][tx * 4 + 0] = f2bf((up.x + lo.x) * 0.5f);
    sS[kk][tx * 4 + 1] = f2bf((up.y + lo.y) * 0.5f);
    sS[kk][tx * 4 + 2] = f2bf((up.z + lo.z) * 0.5f);
    sS[kk][tx * 4 + 3] = f2bf((up.w + lo.w) * 0.5f);
    sD[kk][tx * 4 + 0] = f2bf((up.x - lo.x) * 0.5f);
    sD[kk][tx * 4 + 1] = f2bf((up.y - lo.y) * 0.5f);
    sD[kk][tx * 4 + 2] = f2bf((up.z - lo.z) * 0.5f);
    sD[kk][tx * 4 + 3] = f2bf((up.w - lo.w) * 0.5f);
  }
  __syncthreads();
  #pragma unroll
  for (int r = 0; r < 4; ++r) {
    int cc = ty + r * 16;
    int kq = tx * 4;
    unsigned a0 = sS[kq + 0][cc] | ((unsigned)sS[kq + 1][cc] << 16);
    unsigned a1 = sS[kq + 2][cc] | ((unsigned)sS[kq + 3][cc] << 16);
    *(uint2*)(BsT + (size_t)(c0 + cc) * D + k0 + kq) = make_uint2(a0, a1);
    a0 = sD[kq + 0][cc] | ((unsigned)sD[kq + 1][cc] << 16);
    a1 = sD[kq + 2][cc] | ((unsigned)sD[kq + 3][cc] << 16);
    *(uint2*)(BdT + (size_t)(c0 + cc) * D + k0 + kq) = make_uint2(a0, a1);
  }
}

// ---------------------------------------------------------------------------
// Dual-B bf16 MFMA GEMM (m97 structure):
//   z==0: Cu = w16U @ Bs + |w16U| @ Bd
//   z==1: Cl = w16L @ Bs - |w16L| @ Bd
// 128x128 tile, 4 waves (2x2), 64x64/wave, BK=32, 16x16x32 mfma.
// global_load_lds(16B) with pre-swizzled source; XOR-swizzled ds_read.
// ---------------------------------------------------------------------------
__global__ __launch_bounds__(256) void gemm_dual(
    const unsigned short* __restrict__ w16U,
    const unsigned short* __restrict__ w16L,
    const unsigned short* __restrict__ BsT,
    const unsigned short* __restrict__ BdT,
    float* __restrict__ Cu, float* __restrict__ Cl) {
  const unsigned short* A; float* C; int negd;
  if (blockIdx.z == 0) { A = w16U; C = Cu; negd = 0; }
  else                 { A = w16L; C = Cl; negd = 1; }
  const int row0 = blockIdx.y * 128, col0 = blockIdx.x * 128;

  __shared__ unsigned char AwL[8192];   // [128 rows][32 k] bf16, swizzled
  __shared__ unsigned char BsL[8192];   // [128 cols][32 k] bf16, swizzled
  __shared__ unsigned char BdL[8192];

  const int tid = threadIdx.x;
  const int lane = tid & 63, wid = tid >> 6;
  const int lo = lane & 15, hi = lane >> 4;
  const int wr = wid >> 1, wc = wid & 1;
  const int srow = lane >> 2;            // stage: row within 16-row chunk
  const int soff = (lane & 3) * 16;      // stage: 16B slot within 64B row

  f32x4 acc[4][4] = {};

  for (int kt = 0; kt < D; kt += 32) {
    // ---- stage A, Bs, Bd tiles (each 8KB = 8 chunks of 1KB; wave w: chunks w, w+4)
    #pragma unroll
    for (int c = 0; c < 2; ++c) {
      int ch = wid + c * 4;
      int row = ch * 16 + srow;
      int sw = soff ^ ((row & 3) << 4);       // pre-swizzled source offset
      const unsigned short* gA = A   + (size_t)(row0 + row) * D + kt + (sw >> 1);
      const unsigned short* gS = BsT + (size_t)(col0 + row) * D + kt + (sw >> 1);
      const unsigned short* gD = BdT + (size_t)(col0 + row) * D + kt + (sw >> 1);
      __builtin_amdgcn_global_load_lds((const GLOBAL_AS unsigned int*)gA,
                                       (LDS_AS unsigned int*)(AwL + ch * 1024), 16, 0, 0);
      __builtin_amdgcn_global_load_lds((const GLOBAL_AS unsigned int*)gS,
                                       (LDS_AS unsigned int*)(BsL + ch * 1024), 16, 0, 0);
      __builtin_amdgcn_global_load_lds((const GLOBAL_AS unsigned int*)gD,
                                       (LDS_AS unsigned int*)(BdL + ch * 1024), 16, 0, 0);
    }
    __syncthreads();

    // ---- fragments (swizzled read; |w| and -Bd computed in-register)
    bf16x8 aw[4], av[4], bs[4], bd[4];
    #pragma unroll
    for (int m = 0; m < 4; ++m) {
      int row = wr * 64 + m * 16 + lo;
      int ad = row * 64 + ((hi * 16) ^ ((row & 3) << 4));
      aw[m] = *(const bf16x8*)(AwL + ad);
      av[m] = aw[m] & (short)0x7fff;
    }
    #pragma unroll
    for (int n = 0; n < 4; ++n) {
      int col = wc * 64 + n * 16 + lo;
      int ad = col * 64 + ((hi * 16) ^ ((col & 3) << 4));
      bs[n] = *(const bf16x8*)(BsL + ad);
      bd[n] = *(const bf16x8*)(BdL + ad);
      if (negd) bd[n] ^= (short)0x8000;
    }
    #pragma unroll
    for (int m = 0; m < 4; ++m)
      #pragma unroll
      for (int n = 0; n < 4; ++n) {
        acc[m][n] = __builtin_amdgcn_mfma_f32_16x16x32_bf16(aw[m], bs[n], acc[m][n], 0, 0, 0);
        acc[m][n] = __builtin_amdgcn_mfma_f32_16x16x32_bf16(av[m], bd[n], acc[m][n], 0, 0, 0);
      }
    __syncthreads();
  }

  // ---- epilogue: C/D layout col=lane&15, row=(lane>>4)*4+j
  #pragma unroll
  for (int m = 0; m < 4; ++m)
    #pragma unroll
    for (int n = 0; n < 4; ++n) {
      float* cp = C + (size_t)(row0 + wr * 64 + m * 16 + hi * 4) * D
                    + col0 + wc * 64 + n * 16 + lo;
      #pragma unroll
      for (int j = 0; j < 4; ++j) cp[(size_t)j * D] = acc[m][n][j];
    }
}

// ---------------------------------------------------------------------------
extern "C" void kernel_launch(void* const* d_in, const int* in_sizes, int n_in,
                              void* d_out, int out_size, void* d_ws, size_t ws_size,
                              hipStream_t stream) {
  const float* W_upper = (const float*)d_in[0];
  const float* W_lower = (const float*)d_in[1];
  const float* b_upper = (const float*)d_in[2];
  const float* b_lower = (const float*)d_in[3];
  const float* ub      = (const float*)d_in[4];
  const float* lb      = (const float*)d_in[5];
  float* out = (float*)d_out;
  float* ws  = (float*)d_ws;

  // workspace layout (64MB + 16KB, same as round 1):
  float* curU = ws;                                    // DD f32
  float* curL = ws + DD;                               // DD f32
  unsigned short* w16U = (unsigned short*)(ws + 2 * DD);  // DD bf16
  unsigned short* w16L = w16U + DD;
  unsigned short* BsT  = w16L + DD;
  unsigned short* BdT  = BsT + DD;
  float* bu = (float*)(BdT + DD);                      // D f32
  float* bl = bu + D;

  init_vecs<<<(D + 255) / 256, 256, 0, stream>>>(
      b_upper + 5 * D, b_lower + 5 * D, ub + 5 * D, lb + 5 * D, bu, bl, out);

  const float* cU = W_upper + 5 * DD;
  const float* cL = W_lower + 5 * DD;
  for (int i = 4; i >= 0; --i) {
    concretize<<<D, 256, 0, stream>>>(cU, cL, ub + (size_t)i * D, lb + (size_t)i * D,
                                      b_upper + (size_t)i * D, b_lower + (size_t)i * D,
                                      bu, bl, out, 1);
    conv_A<<<(int)(DD / 8 / 256), 256, 0, stream>>>(cU, cL, w16U, w16L);
    conv_B<<<dim3(32, 32), 256, 0, stream>>>(W_upper + (size_t)i * DD,
                                             W_lower + (size_t)i * DD, BsT, BdT);
    gemm_dual<<<dim3(16, 16, 2), 256, 0, stream>>>(w16U, w16L, BsT, BdT, curU, curL);
    cU = curU; cL = curL;
  }
  concretize<<<D, 256, 0, stream>>>(cU, cL, ub, lb, b_upper, b_lower, bu, bl, out, 0);
}

// Round 5
// 530.125 us; speedup vs baseline: 19.7882x; 1.2399x over previous
//
#include <hip/hip_runtime.h>

#define D 2048
#define DD ((size_t)D * (size_t)D)

typedef __attribute__((ext_vector_type(8))) short bf16x8;
typedef __attribute__((ext_vector_type(16))) float f32x16;

#define GLOBAL_AS __attribute__((address_space(1)))
#define LDS_AS __attribute__((address_space(3)))

__device__ inline unsigned short f2bf(float f) {
  unsigned u = __float_as_uint(f);
  u += 0x7fffu + ((u >> 16) & 1u);
  return (unsigned short)(u >> 16);
}

// ---------------------------------------------------------------------------
__global__ void init_vecs(const float* __restrict__ b_upper5,
                          const float* __restrict__ b_lower5,
                          const float* __restrict__ ub5,
                          const float* __restrict__ lb5,
                          float* __restrict__ bu, float* __restrict__ bl,
                          float* __restrict__ out) {
  int t = blockIdx.x * blockDim.x + threadIdx.x;
  if (t < D) {
    bu[t] = b_upper5[t];
    bl[t] = b_lower5[t];
    out[t] = ub5[t];
    out[D + t] = lb5[t];
  }
}

// ---------------------------------------------------------------------------
// conc_conv: fused concretize + f32->bf16 conversion of the current symbolic
// matrices (they are read once anyway). Block r handles row r (256 thr x 8).
//   cur_ub = pos(Wu_r).ub + neg(Wu_r).lb + bu[r]  -> best_ub = min
//   cur_lb = pos(Wl_r).lb + neg(Wl_r).ub + bl[r]  -> best_lb = max
//   bu[r] += pos(Wu_r).b_up + neg(Wu_r).b_lo   (if update_bias)
//   bl[r] += pos(Wl_r).b_lo + neg(Wl_r).b_up
// plus oU/oL = bf16(Wu/Wl) when write16.
// ---------------------------------------------------------------------------
__global__ __launch_bounds__(256) void conc_conv(
    const float* __restrict__ Wu, const float* __restrict__ Wl,
    const float* __restrict__ ubi, const float* __restrict__ lbi,
    const float* __restrict__ bupi, const float* __restrict__ bloi,
    float* __restrict__ bu, float* __restrict__ bl,
    float* __restrict__ best,
    unsigned short* __restrict__ oU, unsigned short* __restrict__ oL,
    int update_bias, int write16) {
  const int r = blockIdx.x;
  const int t = threadIdx.x;
  const size_t base = (size_t)r * D + t * 8;
  const int c = t * 8;

  float4 wu0 = *(const float4*)(Wu + base), wu1 = *(const float4*)(Wu + base + 4);
  float4 wl0 = *(const float4*)(Wl + base), wl1 = *(const float4*)(Wl + base + 4);
  float4 u0 = *(const float4*)(ubi + c),  u1 = *(const float4*)(ubi + c + 4);
  float4 l0 = *(const float4*)(lbi + c),  l1 = *(const float4*)(lbi + c + 4);
  float4 p0 = *(const float4*)(bupi + c), p1 = *(const float4*)(bupi + c + 4);
  float4 n0 = *(const float4*)(bloi + c), n1 = *(const float4*)(bloi + c + 4);

  float wu[8] = {wu0.x, wu0.y, wu0.z, wu0.w, wu1.x, wu1.y, wu1.z, wu1.w};
  float wl[8] = {wl0.x, wl0.y, wl0.z, wl0.w, wl1.x, wl1.y, wl1.z, wl1.w};
  float uu[8] = {u0.x, u0.y, u0.z, u0.w, u1.x, u1.y, u1.z, u1.w};
  float ll[8] = {l0.x, l0.y, l0.z, l0.w, l1.x, l1.y, l1.z, l1.w};
  float pp[8] = {p0.x, p0.y, p0.z, p0.w, p1.x, p1.y, p1.z, p1.w};
  float nn[8] = {n0.x, n0.y, n0.z, n0.w, n1.x, n1.y, n1.z, n1.w};

  float su_c = 0.f, su_b = 0.f, sl_c = 0.f, sl_b = 0.f;
  #pragma unroll
  for (int j = 0; j < 8; ++j) {
    su_c += wu[j] * (wu[j] >= 0.f ? uu[j] : ll[j]);
    su_b += wu[j] * (wu[j] >= 0.f ? pp[j] : nn[j]);
    sl_c += wl[j] * (wl[j] >= 0.f ? ll[j] : uu[j]);
    sl_b += wl[j] * (wl[j] >= 0.f ? nn[j] : pp[j]);
  }

  if (write16) {
    uint4 w;
    w.x = f2bf(wu[0]) | ((unsigned)f2bf(wu[1]) << 16);
    w.y = f2bf(wu[2]) | ((unsigned)f2bf(wu[3]) << 16);
    w.z = f2bf(wu[4]) | ((unsigned)f2bf(wu[5]) << 16);
    w.w = f2bf(wu[6]) | ((unsigned)f2bf(wu[7]) << 16);
    *(uint4*)(oU + base) = w;
    w.x = f2bf(wl[0]) | ((unsigned)f2bf(wl[1]) << 16);
    w.y = f2bf(wl[2]) | ((unsigned)f2bf(wl[3]) << 16);
    w.z = f2bf(wl[4]) | ((unsigned)f2bf(wl[5]) << 16);
    w.w = f2bf(wl[6]) | ((unsigned)f2bf(wl[7]) << 16);
    *(uint4*)(oL + base) = w;
  }

  #pragma unroll
  for (int off = 32; off; off >>= 1) {
    su_c += __shfl_down(su_c, off);
    su_b += __shfl_down(su_b, off);
    sl_c += __shfl_down(sl_c, off);
    sl_b += __shfl_down(sl_b, off);
  }
  __shared__ float red[4][4];
  int wave = t >> 6;
  if ((t & 63) == 0) {
    red[0][wave] = su_c; red[1][wave] = su_b;
    red[2][wave] = sl_c; red[3][wave] = sl_b;
  }
  __syncthreads();
  if (t == 0) {
    float a = red[0][0] + red[0][1] + red[0][2] + red[0][3];
    float b = red[1][0] + red[1][1] + red[1][2] + red[1][3];
    float cc = red[2][0] + red[2][1] + red[2][2] + red[2][3];
    float d = red[3][0] + red[3][1] + red[3][2] + red[3][3];
    float bu_old = bu[r], bl_old = bl[r];
    best[r]     = fminf(best[r],     a + bu_old);
    best[D + r] = fmaxf(best[D + r], cc + bl_old);
    if (update_bias) {
      bu[r] = b + bu_old;
      bl[r] = d + bl_old;
    }
  }
}

// ---------------------------------------------------------------------------
// conv_B: Bs = (Wup+Wlo)/2, Bd = (Wup-Wlo)/2, written TRANSPOSED ([col][k]).
// Unchanged from round 4 (proven).
// ---------------------------------------------------------------------------
__global__ __launch_bounds__(256) void conv_B(const float* __restrict__ Wup,
                                              const float* __restrict__ Wlo,
                                              unsigned short* __restrict__ BsT,
                                              unsigned short* __restrict__ BdT) {
  __shared__ unsigned short sS[64][68];
  __shared__ unsigned short sD[64][68];
  const int k0 = blockIdx.y * 64, c0 = blockIdx.x * 64;
  const int tx = threadIdx.x & 15, ty = threadIdx.x >> 4;
  #pragma unroll
  for (int r = 0; r < 4; ++r) {
    int kk = ty + r * 16;
    size_t g = (size_t)(k0 + kk) * D + c0 + tx * 4;
    float4 up = *(const float4*)(Wup + g);
    float4 lo = *(const float4*)(Wlo + g);
    sS[kk][tx * 4 + 0] = f2bf((up.x + lo.x) * 0.5f);
    sS[kk][tx * 4 + 1] = f2bf((up.y + lo.y) * 0.5f);
    sS[kk][tx * 4 + 2] = f2bf((up.z + lo.z) * 0.5f);
    sS[kk][tx * 4 + 3] = f2bf((up.w + lo.w) * 0.5f);
    sD[kk][tx * 4 + 0] = f2bf((up.x - lo.x) * 0.5f);
    sD[kk][tx * 4 + 1] = f2bf((up.y - lo.y) * 0.5f);
    sD[kk][tx * 4 + 2] = f2bf((up.z - lo.z) * 0.5f);
    sD[kk][tx * 4 + 3] = f2bf((up.w - lo.w) * 0.5f);
  }
  __syncthreads();
  #pragma unroll
  for (int r = 0; r < 4; ++r) {
    int cc = ty + r * 16;
    int kq = tx * 4;
    unsigned a0 = sS[kq + 0][cc] | ((unsigned)sS[kq + 1][cc] << 16);
    unsigned a1 = sS[kq + 2][cc] | ((unsigned)sS[kq + 3][cc] << 16);
    *(uint2*)(BsT + (size_t)(c0 + cc) * D + k0 + kq) = make_uint2(a0, a1);
    a0 = sD[kq + 0][cc] | ((unsigned)sD[kq + 1][cc] << 16);
    a1 = sD[kq + 2][cc] | ((unsigned)sD[kq + 3][cc] << 16);
    *(uint2*)(BdT + (size_t)(c0 + cc) * D + k0 + kq) = make_uint2(a0, a1);
  }
}

// ---------------------------------------------------------------------------
// Fused dual GEMM, 2-phase pipelined, 32x32x16 MFMA.
//   waves 0-3: Cu = w16U @ Bs + |w16U| @ Bd   (64x64 sub-tile each)
//   waves 4-7: Cl = w16L @ Bs - |w16L| @ Bd
// 128x128 tile, 512 threads, BK=32, LDS 64KB (4 streams x 8KB x dbuf).
// Single __syncthreads per K-tile: stage(next) issued BEFORE compute(cur),
// so global_load_lds latency hides under MFMA (T3 minimum 2-phase recipe).
// ---------------------------------------------------------------------------
__global__ __launch_bounds__(512) void gemm_fused(
    const unsigned short* __restrict__ w16U,
    const unsigned short* __restrict__ w16L,
    const unsigned short* __restrict__ BsT,
    const unsigned short* __restrict__ BdT,
    float* __restrict__ Cu, float* __restrict__ Cl) {
  const int row0 = blockIdx.y * 128, col0 = blockIdx.x * 128;

  // [ AU dbuf 16K | AL dbuf 16K | BS dbuf 16K | BD dbuf 16K ]
  __shared__ unsigned char lds[65536];

  const int tid = threadIdx.x;
  const int lane = tid & 63, wid = tid >> 6;
  const int grp = wid >> 2;            // 0 = upper path, 1 = lower path
  const int w2 = wid & 3;
  const int wr = w2 >> 1, wc = w2 & 1; // 64x64 sub-tile coords
  const int l31 = lane & 31, kh = lane >> 5;

  // staging geometry: wave wid stages chunk wid (rows wid*16..wid*16+15)
  const int srow = lane >> 2;
  const int soff = (lane & 3) * 16;
  const int row = wid * 16 + srow;
  const int sw = soff ^ ((row & 3) << 4);   // pre-swizzled source slot

  const unsigned short* gAU = w16U + (size_t)(row0 + row) * D + (sw >> 1);
  const unsigned short* gAL = w16L + (size_t)(row0 + row) * D + (sw >> 1);
  const unsigned short* gBs = BsT + (size_t)(col0 + row) * D + (sw >> 1);
  const unsigned short* gBd = BdT + (size_t)(col0 + row) * D + (sw >> 1);

  f32x16 acc[2][2] = {};

  // fragment LDS byte offsets (within one 8KB buffer), loop-invariant
  int aoff[2][2], boff[2][2];
  #pragma unroll
  for (int mb = 0; mb < 2; ++mb)
    #pragma unroll
    for (int ks = 0; ks < 2; ++ks) {
      int ar = wr * 64 + mb * 32 + l31;
      aoff[mb][ks] = ar * 64 + ((ks * 32 + kh * 16) ^ ((ar & 3) << 4));
    }
  #pragma unroll
  for (int nb = 0; nb < 2; ++nb)
    #pragma unroll
    for (int ks = 0; ks < 2; ++ks) {
      int bc = wc * 64 + nb * 32 + l31;
      boff[nb][ks] = bc * 64 + ((ks * 32 + kh * 16) ^ ((bc & 3) << 4));
    }

  #define STAGE(curb, kt)                                                          \
    do {                                                                           \
      unsigned dst = (unsigned)(curb) * 8192u + (unsigned)wid * 1024u;             \
      __builtin_amdgcn_global_load_lds((const GLOBAL_AS unsigned*)(gAU + (kt)),    \
          (LDS_AS unsigned*)(lds + 0 + dst), 16, 0, 0);                            \
      __builtin_amdgcn_global_load_lds((const GLOBAL_AS unsigned*)(gAL + (kt)),    \
          (LDS_AS unsigned*)(lds + 16384 + dst), 16, 0, 0);                        \
      __builtin_amdgcn_global_load_lds((const GLOBAL_AS unsigned*)(gBs + (kt)),    \
          (LDS_AS unsigned*)(lds + 32768 + dst), 16, 0, 0);                        \
      __builtin_amdgcn_global_load_lds((const GLOBAL_AS unsigned*)(gBd + (kt)),    \
          (LDS_AS unsigned*)(lds + 49152 + dst), 16, 0, 0);                        \
    } while (0)

  STAGE(0, 0);
  __syncthreads();

  int cur = 0;
  const unsigned Abase = grp ? 16384u : 0u;
  for (int t = 0; t < 64; ++t) {
    if (t < 63) STAGE(cur ^ 1, (t + 1) * 32);

    const unsigned char* Ab = lds + Abase + cur * 8192;
    const unsigned char* Sb = lds + 32768 + cur * 8192;
    const unsigned char* Db = lds + 49152 + cur * 8192;

    bf16x8 aw[2][2], bs[2][2], bd[2][2];
    #pragma unroll
    for (int mb = 0; mb < 2; ++mb)
      #pragma unroll
      for (int ks = 0; ks < 2; ++ks)
        aw[mb][ks] = *(const bf16x8*)(Ab + aoff[mb][ks]);
    #pragma unroll
    for (int nb = 0; nb < 2; ++nb)
      #pragma unroll
      for (int ks = 0; ks < 2; ++ks) {
        bs[nb][ks] = *(const bf16x8*)(Sb + boff[nb][ks]);
        bf16x8 d = *(const bf16x8*)(Db + boff[nb][ks]);
        if (grp) d ^= (short)0x8000;       // lower path uses -Bd
        bd[nb][ks] = d;
      }

    #pragma unroll
    for (int mb = 0; mb < 2; ++mb)
      #pragma unroll
      for (int nb = 0; nb < 2; ++nb)
        #pragma unroll
        for (int ks = 0; ks < 2; ++ks) {
          acc[mb][nb] = __builtin_amdgcn_mfma_f32_32x32x16_bf16(
              aw[mb][ks], bs[nb][ks], acc[mb][nb], 0, 0, 0);
          bf16x8 av = aw[mb][ks] & (short)0x7fff;
          acc[mb][nb] = __builtin_amdgcn_mfma_f32_32x32x16_bf16(
              av, bd[nb][ks], acc[mb][nb], 0, 0, 0);
        }

    __syncthreads();
    cur ^= 1;
  }
  #undef STAGE

  // epilogue: C/D layout col=lane&31, row=(reg&3)+8*(reg>>2)+4*(lane>>5)
  float* C = grp ? Cl : Cu;
  #pragma unroll
  for (int mb = 0; mb < 2; ++mb)
    #pragma unroll
    for (int nb = 0; nb < 2; ++nb) {
      const int colg = col0 + wc * 64 + nb * 32 + l31;
      const int rowb = row0 + wr * 64 + mb * 32 + kh * 4;
      #pragma unroll
      for (int g = 0; g < 4; ++g)
        #pragma unroll
        for (int j = 0; j < 4; ++j)
          C[(size_t)(rowb + g * 8 + j) * D + colg] = acc[mb][nb][g * 4 + j];
    }
}

// ---------------------------------------------------------------------------
extern "C" void kernel_launch(void* const* d_in, const int* in_sizes, int n_in,
                              void* d_out, int out_size, void* d_ws, size_t ws_size,
                              hipStream_t stream) {
  const float* W_upper = (const float*)d_in[0];
  const float* W_lower = (const float*)d_in[1];
  const float* b_upper = (const float*)d_in[2];
  const float* b_lower = (const float*)d_in[3];
  const float* ub      = (const float*)d_in[4];
  const float* lb      = (const float*)d_in[5];
  float* out = (float*)d_out;
  float* ws  = (float*)d_ws;

  float* curU = ws;                                       // DD f32
  float* curL = ws + DD;                                  // DD f32
  unsigned short* w16U = (unsigned short*)(ws + 2 * DD);  // DD bf16
  unsigned short* w16L = w16U + DD;
  unsigned short* BsT  = w16L + DD;
  unsigned short* BdT  = BsT + DD;
  float* bu = (float*)(BdT + DD);                         // D f32
  float* bl = bu + D;

  init_vecs<<<(D + 255) / 256, 256, 0, stream>>>(
      b_upper + 5 * D, b_lower + 5 * D, ub + 5 * D, lb + 5 * D, bu, bl, out);

  const float* cU = W_upper + 5 * DD;
  const float* cL = W_lower + 5 * DD;
  for (int i = 4; i >= 0; --i) {
    conc_conv<<<D, 256, 0, stream>>>(cU, cL, ub + (size_t)i * D, lb + (size_t)i * D,
                                     b_upper + (size_t)i * D, b_lower + (size_t)i * D,
                                     bu, bl, out, w16U, w16L, 1, 1);
    conv_B<<<dim3(32, 32), 256, 0, stream>>>(W_upper + (size_t)i * DD,
                                             W_lower + (size_t)i * DD, BsT, BdT);
    gemm_fused<<<dim3(16, 16), 512, 0, stream>>>(w16U, w16L, BsT, BdT, curU, curL);
    cU = curU; cL = curL;
  }
  conc_conv<<<D, 256, 0, stream>>>(cU, cL, ub, lb, b_upper, b_lower,
                                   bu, bl, out, w16U, w16L, 0, 0);
}

// Round 7
// 508.865 us; speedup vs baseline: 20.6150x; 1.0418x over previous
//
#include <hip/hip_runtime.h>

#define D 2048
#define DD ((size_t)D * (size_t)D)

typedef __attribute__((ext_vector_type(8))) short bf16x8;
typedef __attribute__((ext_vector_type(16))) float f32x16;

#define GLOBAL_AS __attribute__((address_space(1)))
#define LDS_AS __attribute__((address_space(3)))

__device__ inline unsigned short f2bf(float f) {
  unsigned u = __float_as_uint(f);
  u += 0x7fffu + ((u >> 16) & 1u);
  return (unsigned short)(u >> 16);
}

// ---------------------------------------------------------------------------
__global__ void init_vecs(const float* __restrict__ b_upper5,
                          const float* __restrict__ b_lower5,
                          const float* __restrict__ ub5,
                          const float* __restrict__ lb5,
                          float* __restrict__ bu, float* __restrict__ bl,
                          float* __restrict__ out) {
  int t = blockIdx.x * blockDim.x + threadIdx.x;
  if (t < D) {
    bu[t] = b_upper5[t];
    bl[t] = b_lower5[t];
    out[t] = ub5[t];
    out[D + t] = lb5[t];
  }
}

// ---------------------------------------------------------------------------
// prep: fused per-iteration prep pass.
//   blocks [0, 2048):   concretize row r + write bf16 copies of Wu/Wl rows
//   blocks [2048, 3072): conv_B 64x64 tile -> BsT/BdT (transposed bf16)
// ---------------------------------------------------------------------------
__global__ __launch_bounds__(256) void prep(
    const float* __restrict__ Wu, const float* __restrict__ Wl,
    const float* __restrict__ ubi, const float* __restrict__ lbi,
    const float* __restrict__ bupi, const float* __restrict__ bloi,
    float* __restrict__ bu, float* __restrict__ bl,
    float* __restrict__ best,
    unsigned short* __restrict__ oU, unsigned short* __restrict__ oL,
    const float* __restrict__ Wup, const float* __restrict__ Wlo,
    unsigned short* __restrict__ BsT, unsigned short* __restrict__ BdT,
    int update_bias, int write16) {
  __shared__ float red[4][4];
  __shared__ unsigned short sS[64][68];
  __shared__ unsigned short sD[64][68];

  const int t = threadIdx.x;

  if (blockIdx.x < 2048) {
    // ---------------- concretize + conv_A ----------------
    const int r = blockIdx.x;
    const size_t base = (size_t)r * D + t * 8;
    const int c = t * 8;

    float4 wu0 = *(const float4*)(Wu + base), wu1 = *(const float4*)(Wu + base + 4);
    float4 wl0 = *(const float4*)(Wl + base), wl1 = *(const float4*)(Wl + base + 4);
    float4 u0 = *(const float4*)(ubi + c),  u1 = *(const float4*)(ubi + c + 4);
    float4 l0 = *(const float4*)(lbi + c),  l1 = *(const float4*)(lbi + c + 4);
    float4 p0 = *(const float4*)(bupi + c), p1 = *(const float4*)(bupi + c + 4);
    float4 n0 = *(const float4*)(bloi + c), n1 = *(const float4*)(bloi + c + 4);

    float wu[8] = {wu0.x, wu0.y, wu0.z, wu0.w, wu1.x, wu1.y, wu1.z, wu1.w};
    float wl[8] = {wl0.x, wl0.y, wl0.z, wl0.w, wl1.x, wl1.y, wl1.z, wl1.w};
    float uu[8] = {u0.x, u0.y, u0.z, u0.w, u1.x, u1.y, u1.z, u1.w};
    float ll[8] = {l0.x, l0.y, l0.z, l0.w, l1.x, l1.y, l1.z, l1.w};
    float pp[8] = {p0.x, p0.y, p0.z, p0.w, p1.x, p1.y, p1.z, p1.w};
    float nn[8] = {n0.x, n0.y, n0.z, n0.w, n1.x, n1.y, n1.z, n1.w};

    float su_c = 0.f, su_b = 0.f, sl_c = 0.f, sl_b = 0.f;
    #pragma unroll
    for (int j = 0; j < 8; ++j) {
      su_c += wu[j] * (wu[j] >= 0.f ? uu[j] : ll[j]);
      su_b += wu[j] * (wu[j] >= 0.f ? pp[j] : nn[j]);
      sl_c += wl[j] * (wl[j] >= 0.f ? ll[j] : uu[j]);
      sl_b += wl[j] * (wl[j] >= 0.f ? nn[j] : pp[j]);
    }

    if (write16) {
      uint4 w;
      w.x = f2bf(wu[0]) | ((unsigned)f2bf(wu[1]) << 16);
      w.y = f2bf(wu[2]) | ((unsigned)f2bf(wu[3]) << 16);
      w.z = f2bf(wu[4]) | ((unsigned)f2bf(wu[5]) << 16);
      w.w = f2bf(wu[6]) | ((unsigned)f2bf(wu[7]) << 16);
      *(uint4*)(oU + base) = w;
      w.x = f2bf(wl[0]) | ((unsigned)f2bf(wl[1]) << 16);
      w.y = f2bf(wl[2]) | ((unsigned)f2bf(wl[3]) << 16);
      w.z = f2bf(wl[4]) | ((unsigned)f2bf(wl[5]) << 16);
      w.w = f2bf(wl[6]) | ((unsigned)f2bf(wl[7]) << 16);
      *(uint4*)(oL + base) = w;
    }

    #pragma unroll
    for (int off = 32; off; off >>= 1) {
      su_c += __shfl_down(su_c, off);
      su_b += __shfl_down(su_b, off);
      sl_c += __shfl_down(sl_c, off);
      sl_b += __shfl_down(sl_b, off);
    }
    int wave = t >> 6;
    if ((t & 63) == 0) {
      red[0][wave] = su_c; red[1][wave] = su_b;
      red[2][wave] = sl_c; red[3][wave] = sl_b;
    }
    __syncthreads();
    if (t == 0) {
      float a = red[0][0] + red[0][1] + red[0][2] + red[0][3];
      float b = red[1][0] + red[1][1] + red[1][2] + red[1][3];
      float cc = red[2][0] + red[2][1] + red[2][2] + red[2][3];
      float d = red[3][0] + red[3][1] + red[3][2] + red[3][3];
      float bu_old = bu[r], bl_old = bl[r];
      best[r]     = fminf(best[r],     a + bu_old);
      best[D + r] = fmaxf(best[D + r], cc + bl_old);
      if (update_bias) {
        bu[r] = b + bu_old;
        bl[r] = d + bl_old;
      }
    }
  } else {
    // ---------------- conv_B (transposed Bs/Bd) ----------------
    const int bx = blockIdx.x - 2048;
    const int k0 = (bx >> 5) * 64, c0 = (bx & 31) * 64;
    const int tx = t & 15, ty = t >> 4;
    #pragma unroll
    for (int r = 0; r < 4; ++r) {
      int kk = ty + r * 16;
      size_t g = (size_t)(k0 + kk) * D + c0 + tx * 4;
      float4 up = *(const float4*)(Wup + g);
      float4 lo = *(const float4*)(Wlo + g);
      sS[kk][tx * 4 + 0] = f2bf((up.x + lo.x) * 0.5f);
      sS[kk][tx * 4 + 1] = f2bf((up.y + lo.y) * 0.5f);
      sS[kk][tx * 4 + 2] = f2bf((up.z + lo.z) * 0.5f);
      sS[kk][tx * 4 + 3] = f2bf((up.w + lo.w) * 0.5f);
      sD[kk][tx * 4 + 0] = f2bf((up.x - lo.x) * 0.5f);
      sD[kk][tx * 4 + 1] = f2bf((up.y - lo.y) * 0.5f);
      sD[kk][tx * 4 + 2] = f2bf((up.z - lo.z) * 0.5f);
      sD[kk][tx * 4 + 3] = f2bf((up.w - lo.w) * 0.5f);
    }
    __syncthreads();
    #pragma unroll
    for (int r = 0; r < 4; ++r) {
      int cc = ty + r * 16;
      int kq = tx * 4;
      unsigned a0 = sS[kq + 0][cc] | ((unsigned)sS[kq + 1][cc] << 16);
      unsigned a1 = sS[kq + 2][cc] | ((unsigned)sS[kq + 3][cc] << 16);
      *(uint2*)(BsT + (size_t)(c0 + cc) * D + k0 + kq) = make_uint2(a0, a1);
      a0 = sD[kq + 0][cc] | ((unsigned)sD[kq + 1][cc] << 16);
      a1 = sD[kq + 2][cc] | ((unsigned)sD[kq + 3][cc] << 16);
      *(uint2*)(BdT + (size_t)(c0 + cc) * D + k0 + kq) = make_uint2(a0, a1);
    }
  }
}

// ---------------------------------------------------------------------------
// Fused dual GEMM, 2-phase pipelined, 32x32x16 MFMA.
//   waves 0-3: Cu = w16U @ Bs + |w16U| @ Bd   (64x64 sub-tile each)
//   waves 4-7: Cl = w16L @ Bs - |w16L| @ Bd
// 128x128 tile, 512 threads, BK=32, LDS 64KB (4 streams x 8KB x dbuf).
// Swizzle q(row) = ((row>>1)&3)<<4 : combined with the natural row-parity
// bank bit, fragment reads spread over 8 distinct bank-quads per 8 rows
// (4-way residual conflict, best achievable with 4 slots/row).
// ---------------------------------------------------------------------------
__global__ __launch_bounds__(512) void gemm_fused(
    const unsigned short* __restrict__ w16U,
    const unsigned short* __restrict__ w16L,
    const unsigned short* __restrict__ BsT,
    const unsigned short* __restrict__ BdT,
    float* __restrict__ Cu, float* __restrict__ Cl) {
  const int row0 = blockIdx.y * 128, col0 = blockIdx.x * 128;

  // [ AU dbuf 16K | AL dbuf 16K | BS dbuf 16K | BD dbuf 16K ]
  __shared__ unsigned char lds[65536];

  const int tid = threadIdx.x;
  const int lane = tid & 63, wid = tid >> 6;
  const int grp = wid >> 2;            // 0 = upper path, 1 = lower path
  const int w2 = wid & 3;
  const int wr = w2 >> 1, wc = w2 & 1; // 64x64 sub-tile coords
  const int l31 = lane & 31, kh = lane >> 5;

  // staging geometry: wave wid stages chunk wid (rows wid*16..wid*16+15)
  const int srow = lane >> 2;
  const int soff = (lane & 3) * 16;
  const int row = wid * 16 + srow;
  const int sw = soff ^ (((row >> 1) & 3) << 4);   // pre-swizzled source slot

  const unsigned short* gAU = w16U + (size_t)(row0 + row) * D + (sw >> 1);
  const unsigned short* gAL = w16L + (size_t)(row0 + row) * D + (sw >> 1);
  const unsigned short* gBs = BsT + (size_t)(col0 + row) * D + (sw >> 1);
  const unsigned short* gBd = BdT + (size_t)(col0 + row) * D + (sw >> 1);

  f32x16 acc[2][2] = {};

  // fragment LDS byte offsets (within one 8KB buffer), loop-invariant
  int aoff[2][2], boff[2][2];
  #pragma unroll
  for (int mb = 0; mb < 2; ++mb)
    #pragma unroll
    for (int ks = 0; ks < 2; ++ks) {
      int ar = wr * 64 + mb * 32 + l31;
      aoff[mb][ks] = ar * 64 + ((ks * 32 + kh * 16) ^ (((ar >> 1) & 3) << 4));
    }
  #pragma unroll
  for (int nb = 0; nb < 2; ++nb)
    #pragma unroll
    for (int ks = 0; ks < 2; ++ks) {
      int bc = wc * 64 + nb * 32 + l31;
      boff[nb][ks] = bc * 64 + ((ks * 32 + kh * 16) ^ (((bc >> 1) & 3) << 4));
    }

  #define STAGE(curb, kt)                                                          \
    do {                                                                           \
      unsigned dst = (unsigned)(curb) * 8192u + (unsigned)wid * 1024u;             \
      __builtin_amdgcn_global_load_lds((const GLOBAL_AS unsigned*)(gAU + (kt)),    \
          (LDS_AS unsigned*)(lds + 0 + dst), 16, 0, 0);                            \
      __builtin_amdgcn_global_load_lds((const GLOBAL_AS unsigned*)(gAL + (kt)),    \
          (LDS_AS unsigned*)(lds + 16384 + dst), 16, 0, 0);                        \
      __builtin_amdgcn_global_load_lds((const GLOBAL_AS unsigned*)(gBs + (kt)),    \
          (LDS_AS unsigned*)(lds + 32768 + dst), 16, 0, 0);                        \
      __builtin_amdgcn_global_load_lds((const GLOBAL_AS unsigned*)(gBd + (kt)),    \
          (LDS_AS unsigned*)(lds + 49152 + dst), 16, 0, 0);                        \
    } while (0)

  STAGE(0, 0);
  __syncthreads();

  int cur = 0;
  const unsigned Abase = grp ? 16384u : 0u;
  for (int t = 0; t < 64; ++t) {
    if (t < 63) STAGE(cur ^ 1, (t + 1) * 32);

    const unsigned char* Ab = lds + Abase + cur * 8192;
    const unsigned char* Sb = lds + 32768 + cur * 8192;
    const unsigned char* Db = lds + 49152 + cur * 8192;

    bf16x8 aw[2][2], av[2][2], bs[2][2], bd[2][2];
    #pragma unroll
    for (int mb = 0; mb < 2; ++mb)
      #pragma unroll
      for (int ks = 0; ks < 2; ++ks) {
        aw[mb][ks] = *(const bf16x8*)(Ab + aoff[mb][ks]);
        av[mb][ks] = aw[mb][ks] & (short)0x7fff;
      }
    #pragma unroll
    for (int nb = 0; nb < 2; ++nb)
      #pragma unroll
      for (int ks = 0; ks < 2; ++ks) {
        bs[nb][ks] = *(const bf16x8*)(Sb + boff[nb][ks]);
        bf16x8 d = *(const bf16x8*)(Db + boff[nb][ks]);
        if (grp) d ^= (short)0x8000;       // lower path uses -Bd
        bd[nb][ks] = d;
      }

    #pragma unroll
    for (int mb = 0; mb < 2; ++mb)
      #pragma unroll
      for (int nb = 0; nb < 2; ++nb)
        #pragma unroll
        for (int ks = 0; ks < 2; ++ks) {
          acc[mb][nb] = __builtin_amdgcn_mfma_f32_32x32x16_bf16(
              aw[mb][ks], bs[nb][ks], acc[mb][nb], 0, 0, 0);
          acc[mb][nb] = __builtin_amdgcn_mfma_f32_32x32x16_bf16(
              av[mb][ks], bd[nb][ks], acc[mb][nb], 0, 0, 0);
        }

    __syncthreads();
    cur ^= 1;
  }
  #undef STAGE

  // epilogue: C/D layout col=lane&31, row=(reg&3)+8*(reg>>2)+4*(lane>>5)
  float* C = grp ? Cl : Cu;
  #pragma unroll
  for (int mb = 0; mb < 2; ++mb)
    #pragma unroll
    for (int nb = 0; nb < 2; ++nb) {
      const int colg = col0 + wc * 64 + nb * 32 + l31;
      const int rowb = row0 + wr * 64 + mb * 32 + kh * 4;
      #pragma unroll
      for (int g = 0; g < 4; ++g)
        #pragma unroll
        for (int j = 0; j < 4; ++j)
          C[(size_t)(rowb + g * 8 + j) * D + colg] = acc[mb][nb][g * 4 + j];
    }
}

// ---------------------------------------------------------------------------
extern "C" void kernel_launch(void* const* d_in, const int* in_sizes, int n_in,
                              void* d_out, int out_size, void* d_ws, size_t ws_size,
                              hipStream_t stream) {
  const float* W_upper = (const float*)d_in[0];
  const float* W_lower = (const float*)d_in[1];
  const float* b_upper = (const float*)d_in[2];
  const float* b_lower = (const float*)d_in[3];
  const float* ub      = (const float*)d_in[4];
  const float* lb      = (const float*)d_in[5];
  float* out = (float*)d_out;
  float* ws  = (float*)d_ws;

  float* curU = ws;                                       // DD f32
  float* curL = ws + DD;                                  // DD f32
  unsigned short* w16U = (unsigned short*)(ws + 2 * DD);  // DD bf16
  unsigned short* w16L = w16U + DD;
  unsigned short* BsT  = w16L + DD;
  unsigned short* BdT  = BsT + DD;
  float* bu = (float*)(BdT + DD);                         // D f32
  float* bl = bu + D;

  init_vecs<<<(D + 255) / 256, 256, 0, stream>>>(
      b_upper + 5 * D, b_lower + 5 * D, ub + 5 * D, lb + 5 * D, bu, bl, out);

  const float* cU = W_upper + 5 * DD;
  const float* cL = W_lower + 5 * DD;
  for (int i = 4; i >= 0; --i) {
    prep<<<3072, 256, 0, stream>>>(cU, cL, ub + (size_t)i * D, lb + (size_t)i * D,
                                   b_upper + (size_t)i * D, b_lower + (size_t)i * D,
                                   bu, bl, out, w16U, w16L,
                                   W_upper + (size_t)i * DD, W_lower + (size_t)i * DD,
                                   BsT, BdT, 1, 1);
    gemm_fused<<<dim3(16, 16), 512, 0, stream>>>(w16U, w16L, BsT, BdT, curU, curL);
    cU = curU; cL = curL;
  }
  prep<<<2048, 256, 0, stream>>>(cU, cL, ub, lb, b_upper, b_lower,
                                 bu, bl, out, w16U, w16L,
                                 (const float*)nullptr, (const float*)nullptr,
                                 (unsigned short*)nullptr, (unsigned short*)nullptr,
                                 0, 0);
}

// Round 8
// 460.068 us; speedup vs baseline: 22.8015x; 1.1061x over previous
//
#include <hip/hip_runtime.h>

#define D 2048
#define DD ((size_t)D * (size_t)D)

typedef __attribute__((ext_vector_type(8))) short bf16x8;
typedef __attribute__((ext_vector_type(16))) float f32x16;

#define GLOBAL_AS __attribute__((address_space(1)))
#define LDS_AS __attribute__((address_space(3)))

__device__ inline unsigned short f2bf(float f) {
  unsigned u = __float_as_uint(f);
  u += 0x7fffu + ((u >> 16) & 1u);
  return (unsigned short)(u >> 16);
}

// ---------------------------------------------------------------------------
__global__ void init_vecs(const float* __restrict__ b_upper5,
                          const float* __restrict__ b_lower5,
                          const float* __restrict__ ub5,
                          const float* __restrict__ lb5,
                          float* __restrict__ bu, float* __restrict__ bl,
                          float* __restrict__ out) {
  int t = blockIdx.x * blockDim.x + threadIdx.x;
  if (t < D) {
    bu[t] = b_upper5[t];
    bl[t] = b_lower5[t];
    out[t] = ub5[t];
    out[D + t] = lb5[t];
  }
}

// ---------------------------------------------------------------------------
// prep: fused per-iteration prep pass (unchanged from round 7, proven).
//   blocks [0, 2048):   concretize row r + write bf16 copies of Wu/Wl rows
//   blocks [2048, 3072): conv_B 64x64 tile -> BsT/BdT (transposed bf16)
// ---------------------------------------------------------------------------
__global__ __launch_bounds__(256) void prep(
    const float* __restrict__ Wu, const float* __restrict__ Wl,
    const float* __restrict__ ubi, const float* __restrict__ lbi,
    const float* __restrict__ bupi, const float* __restrict__ bloi,
    float* __restrict__ bu, float* __restrict__ bl,
    float* __restrict__ best,
    unsigned short* __restrict__ oU, unsigned short* __restrict__ oL,
    const float* __restrict__ Wup, const float* __restrict__ Wlo,
    unsigned short* __restrict__ BsT, unsigned short* __restrict__ BdT,
    int update_bias, int write16) {
  __shared__ float red[4][4];
  __shared__ unsigned short sS[64][68];
  __shared__ unsigned short sD[64][68];

  const int t = threadIdx.x;

  if (blockIdx.x < 2048) {
    const int r = blockIdx.x;
    const size_t base = (size_t)r * D + t * 8;
    const int c = t * 8;

    float4 wu0 = *(const float4*)(Wu + base), wu1 = *(const float4*)(Wu + base + 4);
    float4 wl0 = *(const float4*)(Wl + base), wl1 = *(const float4*)(Wl + base + 4);
    float4 u0 = *(const float4*)(ubi + c),  u1 = *(const float4*)(ubi + c + 4);
    float4 l0 = *(const float4*)(lbi + c),  l1 = *(const float4*)(lbi + c + 4);
    float4 p0 = *(const float4*)(bupi + c), p1 = *(const float4*)(bupi + c + 4);
    float4 n0 = *(const float4*)(bloi + c), n1 = *(const float4*)(bloi + c + 4);

    float wu[8] = {wu0.x, wu0.y, wu0.z, wu0.w, wu1.x, wu1.y, wu1.z, wu1.w};
    float wl[8] = {wl0.x, wl0.y, wl0.z, wl0.w, wl1.x, wl1.y, wl1.z, wl1.w};
    float uu[8] = {u0.x, u0.y, u0.z, u0.w, u1.x, u1.y, u1.z, u1.w};
    float ll[8] = {l0.x, l0.y, l0.z, l0.w, l1.x, l1.y, l1.z, l1.w};
    float pp[8] = {p0.x, p0.y, p0.z, p0.w, p1.x, p1.y, p1.z, p1.w};
    float nn[8] = {n0.x, n0.y, n0.z, n0.w, n1.x, n1.y, n1.z, n1.w};

    float su_c = 0.f, su_b = 0.f, sl_c = 0.f, sl_b = 0.f;
    #pragma unroll
    for (int j = 0; j < 8; ++j) {
      su_c += wu[j] * (wu[j] >= 0.f ? uu[j] : ll[j]);
      su_b += wu[j] * (wu[j] >= 0.f ? pp[j] : nn[j]);
      sl_c += wl[j] * (wl[j] >= 0.f ? ll[j] : uu[j]);
      sl_b += wl[j] * (wl[j] >= 0.f ? nn[j] : pp[j]);
    }

    if (write16) {
      uint4 w;
      w.x = f2bf(wu[0]) | ((unsigned)f2bf(wu[1]) << 16);
      w.y = f2bf(wu[2]) | ((unsigned)f2bf(wu[3]) << 16);
      w.z = f2bf(wu[4]) | ((unsigned)f2bf(wu[5]) << 16);
      w.w = f2bf(wu[6]) | ((unsigned)f2bf(wu[7]) << 16);
      *(uint4*)(oU + base) = w;
      w.x = f2bf(wl[0]) | ((unsigned)f2bf(wl[1]) << 16);
      w.y = f2bf(wl[2]) | ((unsigned)f2bf(wl[3]) << 16);
      w.z = f2bf(wl[4]) | ((unsigned)f2bf(wl[5]) << 16);
      w.w = f2bf(wl[6]) | ((unsigned)f2bf(wl[7]) << 16);
      *(uint4*)(oL + base) = w;
    }

    #pragma unroll
    for (int off = 32; off; off >>= 1) {
      su_c += __shfl_down(su_c, off);
      su_b += __shfl_down(su_b, off);
      sl_c += __shfl_down(sl_c, off);
      sl_b += __shfl_down(sl_b, off);
    }
    int wave = t >> 6;
    if ((t & 63) == 0) {
      red[0][wave] = su_c; red[1][wave] = su_b;
      red[2][wave] = sl_c; red[3][wave] = sl_b;
    }
    __syncthreads();
    if (t == 0) {
      float a = red[0][0] + red[0][1] + red[0][2] + red[0][3];
      float b = red[1][0] + red[1][1] + red[1][2] + red[1][3];
      float cc = red[2][0] + red[2][1] + red[2][2] + red[2][3];
      float d = red[3][0] + red[3][1] + red[3][2] + red[3][3];
      float bu_old = bu[r], bl_old = bl[r];
      best[r]     = fminf(best[r],     a + bu_old);
      best[D + r] = fmaxf(best[D + r], cc + bl_old);
      if (update_bias) {
        bu[r] = b + bu_old;
        bl[r] = d + bl_old;
      }
    }
  } else {
    const int bx = blockIdx.x - 2048;
    const int k0 = (bx >> 5) * 64, c0 = (bx & 31) * 64;
    const int tx = t & 15, ty = t >> 4;
    #pragma unroll
    for (int r = 0; r < 4; ++r) {
      int kk = ty + r * 16;
      size_t g = (size_t)(k0 + kk) * D + c0 + tx * 4;
      float4 up = *(const float4*)(Wup + g);
      float4 lo = *(const float4*)(Wlo + g);
      sS[kk][tx * 4 + 0] = f2bf((up.x + lo.x) * 0.5f);
      sS[kk][tx * 4 + 1] = f2bf((up.y + lo.y) * 0.5f);
      sS[kk][tx * 4 + 2] = f2bf((up.z + lo.z) * 0.5f);
      sS[kk][tx * 4 + 3] = f2bf((up.w + lo.w) * 0.5f);
      sD[kk][tx * 4 + 0] = f2bf((up.x - lo.x) * 0.5f);
      sD[kk][tx * 4 + 1] = f2bf((up.y - lo.y) * 0.5f);
      sD[kk][tx * 4 + 2] = f2bf((up.z - lo.z) * 0.5f);
      sD[kk][tx * 4 + 3] = f2bf((up.w - lo.w) * 0.5f);
    }
    __syncthreads();
    #pragma unroll
    for (int r = 0; r < 4; ++r) {
      int cc = ty + r * 16;
      int kq = tx * 4;
      unsigned a0 = sS[kq + 0][cc] | ((unsigned)sS[kq + 1][cc] << 16);
      unsigned a1 = sS[kq + 2][cc] | ((unsigned)sS[kq + 3][cc] << 16);
      *(uint2*)(BsT + (size_t)(c0 + cc) * D + k0 + kq) = make_uint2(a0, a1);
      a0 = sD[kq + 0][cc] | ((unsigned)sD[kq + 1][cc] << 16);
      a1 = sD[kq + 2][cc] | ((unsigned)sD[kq + 3][cc] << 16);
      *(uint2*)(BdT + (size_t)(c0 + cc) * D + k0 + kq) = make_uint2(a0, a1);
    }
  }
}

// ---------------------------------------------------------------------------
// Fused dual GEMM, BK=64, 2-phase pipelined, 32x32x16 MFMA.
//   waves 0-3: Cu = w16U @ Bs + |w16U| @ Bd   (64x64 sub-tile each)
//   waves 4-7: Cl = w16L @ Bs - |w16L| @ Bd
// 128x128 tile, 512 threads, dynamic LDS 128KB (4 streams x 16KB x dbuf).
// Stream tile [128 rows][64 k] bf16; rows are 8 x 16B slots; swizzle
// slot ^= (row & 7) on BOTH stage-source and read (involution).
// XCD-aware block swizzle: 32 consecutive tiles (2 full A-panel rows) per XCD.
// ---------------------------------------------------------------------------
__global__ __launch_bounds__(512, 2) void gemm_fused(
    const unsigned short* __restrict__ w16U,
    const unsigned short* __restrict__ w16L,
    const unsigned short* __restrict__ BsT,
    const unsigned short* __restrict__ BdT,
    float* __restrict__ Cu, float* __restrict__ Cl) {
  extern __shared__ unsigned char lds[];

  const int bid = blockIdx.x;
  const int vid = (bid & 7) * 32 + (bid >> 3);   // bijective XCD swizzle (256%8==0)
  const int row0 = (vid >> 4) * 128, col0 = (vid & 15) * 128;

  const int tid = threadIdx.x;
  const int lane = tid & 63, wid = tid >> 6;
  const int grp = wid >> 2;            // 0 = upper path, 1 = lower path
  const int w2 = wid & 3;
  const int wr = w2 >> 1, wc = w2 & 1; // 64x64 sub-tile coords
  const int l31 = lane & 31, kh = lane >> 5;

  // staging: stream tile = 16KB = 16 chunks of 1KB (8 rows x 128B).
  // wave wid stages chunks {wid, wid+8}. lane l -> row_in_chunk l>>3, slot l&7.
  const int srow8 = lane >> 3;
  const int slot  = lane & 7;
  int rowc[2], swel[2];
  #pragma unroll
  for (int c = 0; c < 2; ++c) {
    rowc[c] = (wid + c * 8) * 8 + srow8;
    swel[c] = (slot ^ (rowc[c] & 7)) * 8;      // pre-swizzled source elem offset
  }
  const unsigned short* gAU[2]; const unsigned short* gAL[2];
  const unsigned short* gBs[2]; const unsigned short* gBd[2];
  #pragma unroll
  for (int c = 0; c < 2; ++c) {
    gAU[c] = w16U + (size_t)(row0 + rowc[c]) * D + swel[c];
    gAL[c] = w16L + (size_t)(row0 + rowc[c]) * D + swel[c];
    gBs[c] = BsT + (size_t)(col0 + rowc[c]) * D + swel[c];
    gBd[c] = BdT + (size_t)(col0 + rowc[c]) * D + swel[c];
  }

  f32x16 acc[2][2] = {};

  // fragment LDS byte offsets within a stream (row*128, slot = (ks*2+kh)^(row&7))
  int aoff[2][4], boff[2][4];
  #pragma unroll
  for (int mb = 0; mb < 2; ++mb) {
    int ar = wr * 64 + mb * 32 + l31;
    #pragma unroll
    for (int ks = 0; ks < 4; ++ks)
      aoff[mb][ks] = ar * 128 + (((ks * 2 + kh) ^ (ar & 7)) * 16);
  }
  #pragma unroll
  for (int nb = 0; nb < 2; ++nb) {
    int bc = wc * 64 + nb * 32 + l31;
    #pragma unroll
    for (int ks = 0; ks < 4; ++ks)
      boff[nb][ks] = bc * 128 + (((ks * 2 + kh) ^ (bc & 7)) * 16);
  }

  #define STAGE(curb, kt)                                                          \
    do {                                                                           \
      unsigned bb = (unsigned)(curb) * 65536u;                                     \
      _Pragma("unroll")                                                            \
      for (int c = 0; c < 2; ++c) {                                                \
        unsigned dst = bb + (unsigned)(wid + c * 8) * 1024u;                       \
        __builtin_amdgcn_global_load_lds((const GLOBAL_AS unsigned*)(gAU[c] + (kt)),\
            (LDS_AS unsigned*)(lds + 0 + dst), 16, 0, 0);                          \
        __builtin_amdgcn_global_load_lds((const GLOBAL_AS unsigned*)(gAL[c] + (kt)),\
            (LDS_AS unsigned*)(lds + 16384 + dst), 16, 0, 0);                      \
        __builtin_amdgcn_global_load_lds((const GLOBAL_AS unsigned*)(gBs[c] + (kt)),\
            (LDS_AS unsigned*)(lds + 32768 + dst), 16, 0, 0);                      \
        __builtin_amdgcn_global_load_lds((const GLOBAL_AS unsigned*)(gBd[c] + (kt)),\
            (LDS_AS unsigned*)(lds + 49152 + dst), 16, 0, 0);                      \
      }                                                                            \
    } while (0)

  STAGE(0, 0);
  __syncthreads();

  int cur = 0;
  const unsigned Abase = grp ? 16384u : 0u;
  for (int t = 0; t < 32; ++t) {
    if (t < 31) STAGE(cur ^ 1, (t + 1) * 64);

    const unsigned char* Ab = lds + Abase + cur * 65536;
    const unsigned char* Sb = lds + 32768 + cur * 65536;
    const unsigned char* Db = lds + 49152 + cur * 65536;

    #pragma unroll
    for (int ks = 0; ks < 4; ++ks) {
      bf16x8 aw0 = *(const bf16x8*)(Ab + aoff[0][ks]);
      bf16x8 aw1 = *(const bf16x8*)(Ab + aoff[1][ks]);
      bf16x8 bs0 = *(const bf16x8*)(Sb + boff[0][ks]);
      bf16x8 bs1 = *(const bf16x8*)(Sb + boff[1][ks]);
      bf16x8 bd0 = *(const bf16x8*)(Db + boff[0][ks]);
      bf16x8 bd1 = *(const bf16x8*)(Db + boff[1][ks]);
      if (grp) { bd0 ^= (short)0x8000; bd1 ^= (short)0x8000; }
      bf16x8 av0 = aw0 & (short)0x7fff;
      bf16x8 av1 = aw1 & (short)0x7fff;

      acc[0][0] = __builtin_amdgcn_mfma_f32_32x32x16_bf16(aw0, bs0, acc[0][0], 0, 0, 0);
      acc[0][0] = __builtin_amdgcn_mfma_f32_32x32x16_bf16(av0, bd0, acc[0][0], 0, 0, 0);
      acc[0][1] = __builtin_amdgcn_mfma_f32_32x32x16_bf16(aw0, bs1, acc[0][1], 0, 0, 0);
      acc[0][1] = __builtin_amdgcn_mfma_f32_32x32x16_bf16(av0, bd1, acc[0][1], 0, 0, 0);
      acc[1][0] = __builtin_amdgcn_mfma_f32_32x32x16_bf16(aw1, bs0, acc[1][0], 0, 0, 0);
      acc[1][0] = __builtin_amdgcn_mfma_f32_32x32x16_bf16(av1, bd0, acc[1][0], 0, 0, 0);
      acc[1][1] = __builtin_amdgcn_mfma_f32_32x32x16_bf16(aw1, bs1, acc[1][1], 0, 0, 0);
      acc[1][1] = __builtin_amdgcn_mfma_f32_32x32x16_bf16(av1, bd1, acc[1][1], 0, 0, 0);
    }

    __syncthreads();
    cur ^= 1;
  }
  #undef STAGE

  // epilogue: C/D layout col=lane&31, row=(reg&3)+8*(reg>>2)+4*(lane>>5)
  float* C = grp ? Cl : Cu;
  #pragma unroll
  for (int mb = 0; mb < 2; ++mb)
    #pragma unroll
    for (int nb = 0; nb < 2; ++nb) {
      const int colg = col0 + wc * 64 + nb * 32 + l31;
      const int rowb = row0 + wr * 64 + mb * 32 + kh * 4;
      #pragma unroll
      for (int g = 0; g < 4; ++g)
        #pragma unroll
        for (int j = 0; j < 4; ++j)
          C[(size_t)(rowb + g * 8 + j) * D + colg] = acc[mb][nb][g * 4 + j];
    }
}

// ---------------------------------------------------------------------------
extern "C" void kernel_launch(void* const* d_in, const int* in_sizes, int n_in,
                              void* d_out, int out_size, void* d_ws, size_t ws_size,
                              hipStream_t stream) {
  const float* W_upper = (const float*)d_in[0];
  const float* W_lower = (const float*)d_in[1];
  const float* b_upper = (const float*)d_in[2];
  const float* b_lower = (const float*)d_in[3];
  const float* ub      = (const float*)d_in[4];
  const float* lb      = (const float*)d_in[5];
  float* out = (float*)d_out;
  float* ws  = (float*)d_ws;

  float* curU = ws;                                       // DD f32
  float* curL = ws + DD;                                  // DD f32
  unsigned short* w16U = (unsigned short*)(ws + 2 * DD);  // DD bf16
  unsigned short* w16L = w16U + DD;
  unsigned short* BsT  = w16L + DD;
  unsigned short* BdT  = BsT + DD;
  float* bu = (float*)(BdT + DD);                         // D f32
  float* bl = bu + D;

  static_cast<void>(hipFuncSetAttribute(
      (const void*)gemm_fused, hipFuncAttributeMaxDynamicSharedMemorySize, 131072));

  init_vecs<<<(D + 255) / 256, 256, 0, stream>>>(
      b_upper + 5 * D, b_lower + 5 * D, ub + 5 * D, lb + 5 * D, bu, bl, out);

  const float* cU = W_upper + 5 * DD;
  const float* cL = W_lower + 5 * DD;
  for (int i = 4; i >= 0; --i) {
    prep<<<3072, 256, 0, stream>>>(cU, cL, ub + (size_t)i * D, lb + (size_t)i * D,
                                   b_upper + (size_t)i * D, b_lower + (size_t)i * D,
                                   bu, bl, out, w16U, w16L,
                                   W_upper + (size_t)i * DD, W_lower + (size_t)i * DD,
                                   BsT, BdT, 1, 1);
    gemm_fused<<<256, 512, 131072, stream>>>(w16U, w16L, BsT, BdT, curU, curL);
    cU = curU; cL = curL;
  }
  prep<<<2048, 256, 0, stream>>>(cU, cL, ub, lb, b_upper, b_lower,
                                 bu, bl, out, w16U, w16L,
                                 (const float*)nullptr, (const float*)nullptr,
                                 (unsigned short*)nullptr, (unsigned short*)nullptr,
                                 0, 0);
}